// Round 5
// baseline (140.261 us; speedup 1.0000x reference)
//
#include <hip/hip_runtime.h>
#include <math.h>

// WayfinderAttention: B=1, H=16, T=2048, DH=64, D=64 neighbors. f32 in/out.
// R15: revert R14's QPW=2 (regressed: halved waves, occ 31%). Back to R13
//      geometry (1 query/wave, 4 waves/block) + SINGLE STRUCTURAL DELTA:
//      persistent-ish blocks. Grid 2048 blocks x 4 waves = 8192 waves = exact
//      device wave capacity (32/CU); each block loops over ITERS=4 query
//      groups (16 queries/block). R13's occupancy was 40% with NO resource
//      cap (VGPR 44 -> 8 waves/SIMD ok, LDS 4KB) => block-turnover/dispatch
//      limit on 8192 short blocks. Long-lived blocks fix it; no block
//      barriers exist (LDS per-wave), so loop iterations overlap freely.
//      XCD locality kept: XCD x owns heads {2x,2x+1}; 16|2048 => no block
//      straddles a head boundary.
// Prediction: occupancy 40->75-100%, kernel 46->~27-34us, VALUBusy ->55-70%,
//      FETCH ~20.4MB unchanged, total -> ~95-102.

#define T_DIM 2048
#define DH    64
#define NB    64
#define WPB   4
#define ITERS 4

__global__ __launch_bounds__(WPB * 64)
void wayfinder_attn(const float* __restrict__ q,
                    const float* __restrict__ k,
                    const float* __restrict__ v,
                    const float* __restrict__ etb,
                    const int*   __restrict__ neigh_idx,
                    const int*   __restrict__ edge_type,
                    float*       __restrict__ out)
{
    __shared__ int   j_s[WPB][NB];
    __shared__ float b_s[WPB][NB];
    __shared__ float w_s[WPB][NB];
    __shared__ float dot_s[WPB][NB];

    const int lane = threadIdx.x & 63;
    const int wave = threadIdx.x >> 6;

    // 2048 blocks; round-robin dispatch puts bid&7 on XCD (bid&7).
    // XCD x gets contiguous query range [x*4096, (x+1)*4096) = heads 2x,2x+1
    // (2 MB K+V working set, fits 4 MB L2).
    const int bid  = blockIdx.x;
    const int xcd  = bid & 7;
    const int rank = bid >> 3;                    // 0..255
    const int wq0  = xcd * 4096 + rank * 16 + wave;

    const int c8 = lane & 7;
    const int g8 = lane >> 3;
    const int qw   = lane >> 4;      // quarter 0..3
    const int lp16 = lane & 15;      // dims 4*lp16..4*lp16+3

    for (int it = 0; it < ITERS; ++it) {
        const int wq = wq0 + it * 4;              // this wave's query
        const int t  = wq & (T_DIM - 1);
        const int qbase    = wq * DH;             // floats
        const int headbase = (wq - t) * DH;       // floats
        const float* __restrict__ kh = k + headbase;
        const float* __restrict__ vh = v + headbase;

        // init padding (entries >= nv read as row 0 / bias 0 / weight 0)
        j_s[wave][lane] = 0;
        b_s[wave][lane] = 0.f;

        // per-lane neighbor metadata (lane d owns raw neighbor slot d)
        const int raw = neigh_idx[wq * NB + lane];
        const int et  = edge_type[wq * NB + lane];
        const bool valid = (raw >= 0) && (raw <= t);
        const int  sj    = min(max(raw, 0), T_DIM - 1);
        const float bias = (et != 0) ? etb[et - 1] : 0.f;

        // compaction: valid entries -> positions [0, nv)
        const unsigned long long vb = __ballot(valid);
        const int nv  = __popcll(vb);
        const int pos = __popcll(vb & ((1ull << lane) - 1ull));
        if (valid) { j_s[wave][pos] = sj; b_s[wave][pos] = bias; }

        // ---- score phase: entry e = i*8+g8 gets 8 lanes (c8 dims);
        //      16 independent dwordx4 K loads in flight ----
        const float4 qv0 = *(const float4*)(q + qbase + c8 * 8);
        const float4 qv1 = *(const float4*)(q + qbase + c8 * 8 + 4);

        float4 kr0[8], kr1[8];
        #pragma unroll
        for (int i = 0; i < 8; ++i) {
            if (i * 8 < nv) {
                const int je = j_s[wave][i * 8 + g8];   // >= nv -> row 0 (safe)
                kr0[i] = *(const float4*)(kh + je * DH + c8 * 8);
                kr1[i] = *(const float4*)(kh + je * DH + c8 * 8 + 4);
            }
        }

        #pragma unroll
        for (int i = 0; i < 8; ++i) {
            if (i * 8 < nv) {
                float p = kr0[i].x * qv0.x + kr0[i].y * qv0.y
                        + kr0[i].z * qv0.z + kr0[i].w * qv0.w
                        + kr1[i].x * qv1.x + kr1[i].y * qv1.y
                        + kr1[i].z * qv1.z + kr1[i].w * qv1.w;
                p += __shfl_xor(p, 1, 64);
                p += __shfl_xor(p, 2, 64);
                p += __shfl_xor(p, 4, 64);
                if (c8 == 0) dot_s[wave][i * 8 + g8] = p;   // capture entry e
            }
        }
        const float mydot = dot_s[wave][lane];   // entry 'lane'

        // ---- softmax over compacted entries (lane d = entry d) ----
        const bool dval = lane < nv;
        const float score = dval ? (mydot * 0.125f + b_s[wave][lane]) : -INFINITY;
        float m = score;
        #pragma unroll
        for (int o = 32; o > 0; o >>= 1) m = fmaxf(m, __shfl_xor(m, o, 64));
        const float e = dval ? __expf(score - m) : 0.f;
        float s = e;
        #pragma unroll
        for (int o = 32; o > 0; o >>= 1) s += __shfl_xor(s, o, 64);
        const float w = e / fmaxf(s, 1e-20f);
        w_s[wave][lane] = w;   // entries >= nv get w=0 (padding-safe)

        // ---- PV: quarter qw x 4 entries; 16 lanes x float4 per V row;
        //      all rows prefetched, then f32 accumulate ----
        float4 vr[16];
        #pragma unroll
        for (int i = 0; i < 4; ++i) {
            if (i * 16 < nv) {
                const int4 jd = *(const int4*)&j_s[wave][i * 16 + qw * 4];
                vr[i * 4 + 0] = *(const float4*)(vh + jd.x * DH + lp16 * 4);
                vr[i * 4 + 1] = *(const float4*)(vh + jd.y * DH + lp16 * 4);
                vr[i * 4 + 2] = *(const float4*)(vh + jd.z * DH + lp16 * 4);
                vr[i * 4 + 3] = *(const float4*)(vh + jd.w * DH + lp16 * 4);
            }
        }
        float a0 = 0.f, a1 = 0.f, a2 = 0.f, a3 = 0.f;
        #pragma unroll
        for (int i = 0; i < 4; ++i) {
            if (i * 16 < nv) {
                const float4 wd = *(const float4*)&w_s[wave][i * 16 + qw * 4];
                a0 += wd.x * vr[i * 4 + 0].x;  a1 += wd.x * vr[i * 4 + 0].y;
                a2 += wd.x * vr[i * 4 + 0].z;  a3 += wd.x * vr[i * 4 + 0].w;
                a0 += wd.y * vr[i * 4 + 1].x;  a1 += wd.y * vr[i * 4 + 1].y;
                a2 += wd.y * vr[i * 4 + 1].z;  a3 += wd.y * vr[i * 4 + 1].w;
                a0 += wd.z * vr[i * 4 + 2].x;  a1 += wd.z * vr[i * 4 + 2].y;
                a2 += wd.z * vr[i * 4 + 2].z;  a3 += wd.z * vr[i * 4 + 2].w;
                a0 += wd.w * vr[i * 4 + 3].x;  a1 += wd.w * vr[i * 4 + 3].y;
                a2 += wd.w * vr[i * 4 + 3].z;  a3 += wd.w * vr[i * 4 + 3].w;
            }
        }
        // reduce across quarters (butterfly), lanes 0..15 store float4
        a0 += __shfl_xor(a0, 16, 64);  a1 += __shfl_xor(a1, 16, 64);
        a2 += __shfl_xor(a2, 16, 64);  a3 += __shfl_xor(a3, 16, 64);
        a0 += __shfl_xor(a0, 32, 64);  a1 += __shfl_xor(a1, 32, 64);
        a2 += __shfl_xor(a2, 32, 64);  a3 += __shfl_xor(a3, 32, 64);
        if (lane < 16) {
            float4 o; o.x = a0; o.y = a1; o.z = a2; o.w = a3;
            *(float4*)(out + qbase + lane * 4) = o;
        }
    }
}

extern "C" void kernel_launch(void* const* d_in, const int* in_sizes, int n_in,
                              void* d_out, int out_size, void* d_ws, size_t ws_size,
                              hipStream_t stream)
{
    const float* q   = (const float*)d_in[0];
    const float* k   = (const float*)d_in[1];
    const float* v   = (const float*)d_in[2];
    const float* etb = (const float*)d_in[3];
    const int* neigh_idx = (const int*)d_in[4];
    const int* edge_type = (const int*)d_in[5];
    float* out = (float*)d_out;

    (void)d_ws; (void)ws_size;

    // 32768 queries / (4 waves * 4 iters) = 2048 blocks = exact wave capacity
    hipLaunchKernelGGL(wayfinder_attn, dim3(2048), dim3(WPB * 64),
                       0, stream, q, k, v, etb, neigh_idx, edge_type, out);
}

// Round 6
// 113.027 us; speedup vs baseline: 1.2410x; 1.2410x over previous
//
#include <hip/hip_runtime.h>
#include <hip/hip_fp16.h>
#include <math.h>

// WayfinderAttention: B=1, H=16, T=2048, DH=64, D=64 neighbors. f32 in/out.
// R16: revert R14/R15 concurrency experiments (both regressed: fewer blocks =
//      worse; R15 VGPR 88 -> occ 17%). HARNESS CORRECTION from R13/R15 traces:
//      256MiB ws poison fills run UNCONDITIONALLY (even when d_ws unused), so
//      the f16 workspace path costs only ~5us convert, not 45us. Fixed
//      overhead ~69us; f16 attn ~37us (R11), f32 attn ~46us (R13).
// DELTA: combine the two proven independent wins, never yet run together:
//      R11's f16-KV kernel (halves gather lines: 128B row = 1 L2 line) +
//      R13's XCD swizzle (8192 blocks -> 1024/XCD = 2 heads = 1MB f16 KV
//      working set per XCD L2).
// Prediction: attn kernel ~31-35us, FETCH ~12-16MB, total 112.4 -> ~104-108.

#define T_DIM 2048
#define DH    64
#define NB    64
#define WPB   4
#define KV_ELEMS (16 * T_DIM * DH)   // 2,097,152 per tensor

typedef _Float16 h2_t __attribute__((ext_vector_type(2)));

// ---------------- prepass: f32 -> f16 (RTN), K then V ----------------
__global__ __launch_bounds__(256)
void convert_kv_kernel(const float* __restrict__ k, const float* __restrict__ v,
                       unsigned int* __restrict__ ws)
{
    const int tid = blockIdx.x * 256 + threadIdx.x;     // [0, KV_ELEMS/4)
    unsigned int* kh = ws;
    unsigned int* vh = ws + (KV_ELEMS / 2);
    const float4 kv = *(const float4*)(k + (long long)tid * 4);
    const float4 vv = *(const float4*)(v + (long long)tid * 4);
    h2_t k0 = { (_Float16)kv.x, (_Float16)kv.y };
    h2_t k1 = { (_Float16)kv.z, (_Float16)kv.w };
    h2_t v0 = { (_Float16)vv.x, (_Float16)vv.y };
    h2_t v1 = { (_Float16)vv.z, (_Float16)vv.w };
    uint2 pk, pv;
    pk.x = __builtin_bit_cast(unsigned int, k0);
    pk.y = __builtin_bit_cast(unsigned int, k1);
    pv.x = __builtin_bit_cast(unsigned int, v0);
    pv.y = __builtin_bit_cast(unsigned int, v1);
    *(uint2*)(kh + tid * 2) = pk;
    *(uint2*)(vh + tid * 2) = pv;
}

__device__ __forceinline__ float f16lo(unsigned int u) {
    return __low2float(__builtin_bit_cast(__half2, u));
}
__device__ __forceinline__ float f16hi(unsigned int u) {
    return __high2float(__builtin_bit_cast(__half2, u));
}

__device__ __forceinline__ float dot2f(unsigned int ku, h2_t qh, float c) {
#if __has_builtin(__builtin_amdgcn_fdot2)
    return __builtin_amdgcn_fdot2(__builtin_bit_cast(h2_t, ku), qh, c, false);
#else
    return c + f16lo(ku) * (float)qh.x + f16hi(ku) * (float)qh.y;
#endif
}

// ---------------- main kernel (f16 gathers, compacted, XCD-swizzled) --------
__global__ __launch_bounds__(WPB * 64)
void wayfinder_attn_f16(const float* __restrict__ q,
                        const unsigned int* __restrict__ kvws,
                        const float* __restrict__ etb,
                        const int*   __restrict__ neigh_idx,
                        const int*   __restrict__ edge_type,
                        float*       __restrict__ out)
{
    __shared__ int   j_s[WPB][NB];
    __shared__ float b_s[WPB][NB];
    __shared__ float w_s[WPB][NB];
    __shared__ float dot_s[WPB][NB];

    const int lane = threadIdx.x & 63;
    const int wave = threadIdx.x >> 6;

    // R16 delta: XCD swizzle. 8192 blocks round-robin across 8 XCDs;
    // swz gives XCD x the contiguous range [x*1024,(x+1)*1024) = heads
    // {2x,2x+1} = 1 MB f16 K+V working set (fits 4 MB per-XCD L2).
    const int bid = blockIdx.x;
    const int swz = (bid & 7) * 1024 + (bid >> 3);

    const int wq   = swz * WPB + wave;              // flat h*T + t (B=1)
    const int t    = wq & (T_DIM - 1);
    const int qbase    = wq * DH;
    const int headbase = (wq - t) * DH;             // floats
    const unsigned int* __restrict__ kh = kvws + (headbase >> 1);
    const unsigned int* __restrict__ vh = kvws + (KV_ELEMS / 2) + (headbase >> 1);

    // init padding (entries >= nv read as row 0 / bias 0)
    j_s[wave][lane] = 0;
    b_s[wave][lane] = 0.f;

    // per-lane neighbor metadata (lane d owns raw neighbor slot d)
    const int raw = neigh_idx[wq * NB + lane];
    const int et  = edge_type[wq * NB + lane];
    const bool valid = (raw >= 0) && (raw <= t);
    const int  sj    = min(max(raw, 0), T_DIM - 1);
    const float bias = (et != 0) ? etb[et - 1] : 0.f;

    // compaction: valid entries -> positions [0, nv)
    const unsigned long long vb = __ballot(valid);
    const int nv  = __popcll(vb);
    const int pos = __popcll(vb & ((1ull << lane) - 1ull));
    if (valid) { j_s[wave][pos] = sj; b_s[wave][pos] = bias; }

    // ---- score phase: iteration i covers entries i*8..i*8+7; group g8
    //      handles entry e = i*8+g8. Guard i*8<nv is wave-uniform. ----
    const int c8 = lane & 7;
    const int g8 = lane >> 3;
    const float4 qv0 = *(const float4*)(q + qbase + c8 * 8);
    const float4 qv1 = *(const float4*)(q + qbase + c8 * 8 + 4);
    // q pre-rounded to packed f16 for v_dot2_f32_f16 (adds ~1e-3 to scores)
    const h2_t qh0 = { (_Float16)qv0.x, (_Float16)qv0.y };
    const h2_t qh1 = { (_Float16)qv0.z, (_Float16)qv0.w };
    const h2_t qh2 = { (_Float16)qv1.x, (_Float16)qv1.y };
    const h2_t qh3 = { (_Float16)qv1.z, (_Float16)qv1.w };

    // prefetch: up to ceil(nv/8) independent dwordx4 loads in flight.
    uint4 kr[8];
    #pragma unroll
    for (int i = 0; i < 8; ++i) {
        if (i * 8 < nv) {
            const int je = j_s[wave][i * 8 + g8];   // entries >= nv -> row 0 (safe)
            kr[i] = *(const uint4*)(kh + je * 32 + c8 * 4);  // dims 8c8..8c8+7
        }
    }

    #pragma unroll
    for (int i = 0; i < 8; ++i) {
        if (i * 8 < nv) {
            const uint4 u = kr[i];
            float p = dot2f(u.x, qh0, 0.f);
            p = dot2f(u.y, qh1, p);
            p = dot2f(u.z, qh2, p);
            p = dot2f(u.w, qh3, p);
            p += __shfl_xor(p, 1, 64);
            p += __shfl_xor(p, 2, 64);
            p += __shfl_xor(p, 4, 64);
            if (c8 == 0) dot_s[wave][i * 8 + g8] = p;   // capture entry e
        }
    }
    const float mydot = dot_s[wave][lane];   // entry 'lane' (garbage if >= nv)

    // ---- softmax over compacted entries (lane d = entry d) ----
    const bool dval = lane < nv;
    const float score = dval ? (mydot * 0.125f + b_s[wave][lane]) : -INFINITY;
    float m = score;
    #pragma unroll
    for (int o = 32; o > 0; o >>= 1) m = fmaxf(m, __shfl_xor(m, o, 64));
    const float e = dval ? __expf(score - m) : 0.f;
    float s = e;
    #pragma unroll
    for (int o = 32; o > 0; o >>= 1) s += __shfl_xor(s, o, 64);
    const float w = e / fmaxf(s, 1e-20f);
    w_s[wave][lane] = w;   // entries >= nv get w=0 (padding-safe)

    // ---- PV: quarter qw takes contiguous entries base+qw*4..+3 (vector LDS
    //      broadcasts); 16 lanes x 8B per V row; f32 accumulate ----
    const int qw   = lane >> 4;      // quarter 0..3
    const int lp16 = lane & 15;      // dims 4*lp16..4*lp16+3
    float a0 = 0.f, a1 = 0.f, a2 = 0.f, a3 = 0.f;
    for (int base = 0; base < nv; base += 16) {
        const int eb = base + qw * 4;
        const int4   jd = *(const int4*)&j_s[wave][eb];
        const float4 wd = *(const float4*)&w_s[wave][eb];
        const uint2 u0 = *(const uint2*)(vh + jd.x * 32 + lp16 * 2);
        const uint2 u1 = *(const uint2*)(vh + jd.y * 32 + lp16 * 2);
        const uint2 u2 = *(const uint2*)(vh + jd.z * 32 + lp16 * 2);
        const uint2 u3 = *(const uint2*)(vh + jd.w * 32 + lp16 * 2);
        a0 += wd.x * f16lo(u0.x);  a1 += wd.x * f16hi(u0.x);
        a2 += wd.x * f16lo(u0.y);  a3 += wd.x * f16hi(u0.y);
        a0 += wd.y * f16lo(u1.x);  a1 += wd.y * f16hi(u1.x);
        a2 += wd.y * f16lo(u1.y);  a3 += wd.y * f16hi(u1.y);
        a0 += wd.z * f16lo(u2.x);  a1 += wd.z * f16hi(u2.x);
        a2 += wd.z * f16lo(u2.y);  a3 += wd.z * f16hi(u2.y);
        a0 += wd.w * f16lo(u3.x);  a1 += wd.w * f16hi(u3.x);
        a2 += wd.w * f16lo(u3.y);  a3 += wd.w * f16hi(u3.y);
    }
    // reduce across quarters (butterfly), then lanes 0..15 store float4
    a0 += __shfl_xor(a0, 16, 64);  a1 += __shfl_xor(a1, 16, 64);
    a2 += __shfl_xor(a2, 16, 64);  a3 += __shfl_xor(a3, 16, 64);
    a0 += __shfl_xor(a0, 32, 64);  a1 += __shfl_xor(a1, 32, 64);
    a2 += __shfl_xor(a2, 32, 64);  a3 += __shfl_xor(a3, 32, 64);
    if (lane < 16) {
        float4 o; o.x = a0; o.y = a1; o.z = a2; o.w = a3;
        *(float4*)(out + qbase + lane * 4) = o;
    }
}

// ---------------- fallback (R3, f32, no workspace) ----------------
__global__ __launch_bounds__(WPB * 64)
void wayfinder_attn_f32(const float* __restrict__ q,
                        const float* __restrict__ k,
                        const float* __restrict__ v,
                        const float* __restrict__ etb,
                        const int*   __restrict__ neigh_idx,
                        const int*   __restrict__ edge_type,
                        float*       __restrict__ out)
{
    __shared__ int   j_s[WPB][NB];
    __shared__ float w_s[WPB][NB];

    const int lane = threadIdx.x & 63;
    const int wave = threadIdx.x >> 6;
    const int wq   = blockIdx.x * WPB + wave;
    const int t    = wq & (T_DIM - 1);
    const long long qbase    = (long long)wq * DH;
    const long long headbase = (long long)(wq - t) * DH;

    const long long nbase = (long long)wq * NB;
    const int raw = neigh_idx[nbase + lane];
    const int et  = edge_type[nbase + lane];
    const bool valid = (raw >= 0) && (raw <= t);
    const int  sj   = min(max(raw, 0), T_DIM - 1);
    j_s[wave][lane] = sj;

    const int c = lane & 15;
    const int g = lane >> 4;
    const float4 qv = *(const float4*)(q + qbase + c * 4);

    int jarr[16];
    {
        const int4* jg = (const int4*)&j_s[wave][g * 16];
        *(int4*)&jarr[0]  = jg[0];
        *(int4*)&jarr[4]  = jg[1];
        *(int4*)&jarr[8]  = jg[2];
        *(int4*)&jarr[12] = jg[3];
    }

    const float* __restrict__ khead = k + headbase;
    float mydot = 0.f;
    #pragma unroll
    for (int i = 0; i < 16; ++i) {
        const float4 kv = *(const float4*)(khead + (long long)jarr[i] * DH + c * 4);
        float p = kv.x * qv.x + kv.y * qv.y + kv.z * qv.z + kv.w * qv.w;
        p += __shfl_xor(p, 1, 64);
        p += __shfl_xor(p, 2, 64);
        p += __shfl_xor(p, 4, 64);
        p += __shfl_xor(p, 8, 64);
        if (c == i) mydot = p;
    }

    const float bias  = (et != 0) ? etb[et - 1] : 0.f;
    const float score = valid ? (mydot * 0.125f + bias) : -INFINITY;

    float m = score;
    #pragma unroll
    for (int o = 32; o > 0; o >>= 1) m = fmaxf(m, __shfl_xor(m, o, 64));
    const float e = valid ? __expf(score - m) : 0.f;
    float s = e;
    #pragma unroll
    for (int o = 32; o > 0; o >>= 1) s += __shfl_xor(s, o, 64);
    const float w = e / fmaxf(s, 1e-20f);
    w_s[wave][lane] = w;

    const float* __restrict__ vhead = v + headbase;
    float acc = 0.f;
    #pragma unroll
    for (int d4 = 0; d4 < 16; ++d4) {
        const float4 wd = *(const float4*)&w_s[wave][d4 * 4];
        const int4   jd = *(const int4*)&j_s[wave][d4 * 4];
        acc += wd.x * vhead[(long long)jd.x * DH + lane];
        acc += wd.y * vhead[(long long)jd.y * DH + lane];
        acc += wd.z * vhead[(long long)jd.z * DH + lane];
        acc += wd.w * vhead[(long long)jd.w * DH + lane];
    }
    out[qbase + lane] = acc;
}

extern "C" void kernel_launch(void* const* d_in, const int* in_sizes, int n_in,
                              void* d_out, int out_size, void* d_ws, size_t ws_size,
                              hipStream_t stream)
{
    const float* q   = (const float*)d_in[0];
    const float* k   = (const float*)d_in[1];
    const float* v   = (const float*)d_in[2];
    const float* etb = (const float*)d_in[3];
    const int* neigh_idx = (const int*)d_in[4];
    const int* edge_type = (const int*)d_in[5];
    float* out = (float*)d_out;

    const int total_queries = 16 * T_DIM;     // 32768
    const int blocks = total_queries / WPB;   // 8192
    const size_t need = (size_t)KV_ELEMS * 2 * sizeof(unsigned short); // 8 MB

    if (ws_size >= need) {
        unsigned int* ws = (unsigned int*)d_ws;
        hipLaunchKernelGGL(convert_kv_kernel, dim3(KV_ELEMS / 4 / 256), dim3(256),
                           0, stream, k, v, ws);
        hipLaunchKernelGGL(wayfinder_attn_f16, dim3(blocks), dim3(WPB * 64),
                           0, stream, q, ws, etb, neigh_idx, edge_type, out);
    } else {
        hipLaunchKernelGGL(wayfinder_attn_f32, dim3(blocks), dim3(WPB * 64),
                           0, stream, q, k, v, etb, neigh_idx, edge_type, out);
    }
}

// Round 7
// 110.987 us; speedup vs baseline: 1.2638x; 1.0184x over previous
//
#include <hip/hip_runtime.h>
#include <hip/hip_fp16.h>
#include <math.h>

// WayfinderAttention: B=1, H=16, T=2048, DH=64, D=64 neighbors. f32 in/out.
// R17: R16 (f16+swizzle, total 113.0 ~= R11 112.4; swizzle neutral on f16 but
//      kept). Session model: total = ~70us fixed harness + ~5us convert +
//      ~37us attn. Remaining lever = attn kernel only.
// SINGLE KNOB: WPB 4 -> 2 (128-thread blocks, 16384 blocks, SAME 32768 waves).
//      R13->R15 trend: residency scales with BLOCK COUNT (8192blk/40% ->
//      4096/31% -> 2048/17%) while no resource caps occupancy (VGPR 44,
//      LDS 4KB) => per-CU workgroup-slot granularity limits residency.
//      Smaller+more blocks should raise resident waves at constant total.
// Prediction: occ 40->55-70%, attn ~37->28-32us, total -> ~104-108.
//      If neutral: declare serial-chain floor / effective roofline.

#define T_DIM 2048
#define DH    64
#define NB    64
#define WPB   2
#define KV_ELEMS (16 * T_DIM * DH)   // 2,097,152 per tensor

typedef _Float16 h2_t __attribute__((ext_vector_type(2)));

// ---------------- prepass: f32 -> f16 (RTN), K then V ----------------
__global__ __launch_bounds__(256)
void convert_kv_kernel(const float* __restrict__ k, const float* __restrict__ v,
                       unsigned int* __restrict__ ws)
{
    const int tid = blockIdx.x * 256 + threadIdx.x;     // [0, KV_ELEMS/4)
    unsigned int* kh = ws;
    unsigned int* vh = ws + (KV_ELEMS / 2);
    const float4 kv = *(const float4*)(k + (long long)tid * 4);
    const float4 vv = *(const float4*)(v + (long long)tid * 4);
    h2_t k0 = { (_Float16)kv.x, (_Float16)kv.y };
    h2_t k1 = { (_Float16)kv.z, (_Float16)kv.w };
    h2_t v0 = { (_Float16)vv.x, (_Float16)vv.y };
    h2_t v1 = { (_Float16)vv.z, (_Float16)vv.w };
    uint2 pk, pv;
    pk.x = __builtin_bit_cast(unsigned int, k0);
    pk.y = __builtin_bit_cast(unsigned int, k1);
    pv.x = __builtin_bit_cast(unsigned int, v0);
    pv.y = __builtin_bit_cast(unsigned int, v1);
    *(uint2*)(kh + tid * 2) = pk;
    *(uint2*)(vh + tid * 2) = pv;
}

__device__ __forceinline__ float f16lo(unsigned int u) {
    return __low2float(__builtin_bit_cast(__half2, u));
}
__device__ __forceinline__ float f16hi(unsigned int u) {
    return __high2float(__builtin_bit_cast(__half2, u));
}

__device__ __forceinline__ float dot2f(unsigned int ku, h2_t qh, float c) {
#if __has_builtin(__builtin_amdgcn_fdot2)
    return __builtin_amdgcn_fdot2(__builtin_bit_cast(h2_t, ku), qh, c, false);
#else
    return c + f16lo(ku) * (float)qh.x + f16hi(ku) * (float)qh.y;
#endif
}

// ---------------- main kernel (f16 gathers, compacted, XCD-swizzled) --------
__global__ __launch_bounds__(WPB * 64)
void wayfinder_attn_f16(const float* __restrict__ q,
                        const unsigned int* __restrict__ kvws,
                        const float* __restrict__ etb,
                        const int*   __restrict__ neigh_idx,
                        const int*   __restrict__ edge_type,
                        float*       __restrict__ out)
{
    __shared__ int   j_s[WPB][NB];
    __shared__ float b_s[WPB][NB];
    __shared__ float w_s[WPB][NB];
    __shared__ float dot_s[WPB][NB];

    const int lane = threadIdx.x & 63;
    const int wave = threadIdx.x >> 6;

    // XCD swizzle: 16384 blocks round-robin across 8 XCDs; swz gives XCD x
    // the contiguous range [x*2048,(x+1)*2048) = queries [x*4096,(x+1)*4096)
    // = heads {2x,2x+1} (1 MB f16 K+V working set per 4 MB XCD L2).
    const int bid = blockIdx.x;
    const int swz = (bid & 7) * 2048 + (bid >> 3);

    const int wq   = swz * WPB + wave;              // flat h*T + t (B=1)
    const int t    = wq & (T_DIM - 1);
    const int qbase    = wq * DH;
    const int headbase = (wq - t) * DH;             // floats
    const unsigned int* __restrict__ kh = kvws + (headbase >> 1);
    const unsigned int* __restrict__ vh = kvws + (KV_ELEMS / 2) + (headbase >> 1);

    // init padding (entries >= nv read as row 0 / bias 0)
    j_s[wave][lane] = 0;
    b_s[wave][lane] = 0.f;

    // per-lane neighbor metadata (lane d owns raw neighbor slot d)
    const int raw = neigh_idx[wq * NB + lane];
    const int et  = edge_type[wq * NB + lane];
    const bool valid = (raw >= 0) && (raw <= t);
    const int  sj    = min(max(raw, 0), T_DIM - 1);
    const float bias = (et != 0) ? etb[et - 1] : 0.f;

    // compaction: valid entries -> positions [0, nv)
    const unsigned long long vb = __ballot(valid);
    const int nv  = __popcll(vb);
    const int pos = __popcll(vb & ((1ull << lane) - 1ull));
    if (valid) { j_s[wave][pos] = sj; b_s[wave][pos] = bias; }

    // ---- score phase: iteration i covers entries i*8..i*8+7; group g8
    //      handles entry e = i*8+g8. Guard i*8<nv is wave-uniform. ----
    const int c8 = lane & 7;
    const int g8 = lane >> 3;
    const float4 qv0 = *(const float4*)(q + qbase + c8 * 8);
    const float4 qv1 = *(const float4*)(q + qbase + c8 * 8 + 4);
    // q pre-rounded to packed f16 for v_dot2_f32_f16 (adds ~1e-3 to scores)
    const h2_t qh0 = { (_Float16)qv0.x, (_Float16)qv0.y };
    const h2_t qh1 = { (_Float16)qv0.z, (_Float16)qv0.w };
    const h2_t qh2 = { (_Float16)qv1.x, (_Float16)qv1.y };
    const h2_t qh3 = { (_Float16)qv1.z, (_Float16)qv1.w };

    // prefetch: up to ceil(nv/8) independent dwordx4 loads in flight.
    uint4 kr[8];
    #pragma unroll
    for (int i = 0; i < 8; ++i) {
        if (i * 8 < nv) {
            const int je = j_s[wave][i * 8 + g8];   // entries >= nv -> row 0 (safe)
            kr[i] = *(const uint4*)(kh + je * 32 + c8 * 4);  // dims 8c8..8c8+7
        }
    }

    #pragma unroll
    for (int i = 0; i < 8; ++i) {
        if (i * 8 < nv) {
            const uint4 u = kr[i];
            float p = dot2f(u.x, qh0, 0.f);
            p = dot2f(u.y, qh1, p);
            p = dot2f(u.z, qh2, p);
            p = dot2f(u.w, qh3, p);
            p += __shfl_xor(p, 1, 64);
            p += __shfl_xor(p, 2, 64);
            p += __shfl_xor(p, 4, 64);
            if (c8 == 0) dot_s[wave][i * 8 + g8] = p;   // capture entry e
        }
    }
    const float mydot = dot_s[wave][lane];   // entry 'lane' (garbage if >= nv)

    // ---- softmax over compacted entries (lane d = entry d) ----
    const bool dval = lane < nv;
    const float score = dval ? (mydot * 0.125f + b_s[wave][lane]) : -INFINITY;
    float m = score;
    #pragma unroll
    for (int o = 32; o > 0; o >>= 1) m = fmaxf(m, __shfl_xor(m, o, 64));
    const float e = dval ? __expf(score - m) : 0.f;
    float s = e;
    #pragma unroll
    for (int o = 32; o > 0; o >>= 1) s += __shfl_xor(s, o, 64);
    const float w = e / fmaxf(s, 1e-20f);
    w_s[wave][lane] = w;   // entries >= nv get w=0 (padding-safe)

    // ---- PV: quarter qw takes contiguous entries base+qw*4..+3 (vector LDS
    //      broadcasts); 16 lanes x 8B per V row; f32 accumulate ----
    const int qw   = lane >> 4;      // quarter 0..3
    const int lp16 = lane & 15;      // dims 4*lp16..4*lp16+3
    float a0 = 0.f, a1 = 0.f, a2 = 0.f, a3 = 0.f;
    for (int base = 0; base < nv; base += 16) {
        const int eb = base + qw * 4;
        const int4   jd = *(const int4*)&j_s[wave][eb];
        const float4 wd = *(const float4*)&w_s[wave][eb];
        const uint2 u0 = *(const uint2*)(vh + jd.x * 32 + lp16 * 2);
        const uint2 u1 = *(const uint2*)(vh + jd.y * 32 + lp16 * 2);
        const uint2 u2 = *(const uint2*)(vh + jd.z * 32 + lp16 * 2);
        const uint2 u3 = *(const uint2*)(vh + jd.w * 32 + lp16 * 2);
        a0 += wd.x * f16lo(u0.x);  a1 += wd.x * f16hi(u0.x);
        a2 += wd.x * f16lo(u0.y);  a3 += wd.x * f16hi(u0.y);
        a0 += wd.y * f16lo(u1.x);  a1 += wd.y * f16hi(u1.x);
        a2 += wd.y * f16lo(u1.y);  a3 += wd.y * f16hi(u1.y);
        a0 += wd.z * f16lo(u2.x);  a1 += wd.z * f16hi(u2.x);
        a2 += wd.z * f16lo(u2.y);  a3 += wd.z * f16hi(u2.y);
        a0 += wd.w * f16lo(u3.x);  a1 += wd.w * f16hi(u3.x);
        a2 += wd.w * f16lo(u3.y);  a3 += wd.w * f16hi(u3.y);
    }
    // reduce across quarters (butterfly), then lanes 0..15 store float4
    a0 += __shfl_xor(a0, 16, 64);  a1 += __shfl_xor(a1, 16, 64);
    a2 += __shfl_xor(a2, 16, 64);  a3 += __shfl_xor(a3, 16, 64);
    a0 += __shfl_xor(a0, 32, 64);  a1 += __shfl_xor(a1, 32, 64);
    a2 += __shfl_xor(a2, 32, 64);  a3 += __shfl_xor(a3, 32, 64);
    if (lane < 16) {
        float4 o; o.x = a0; o.y = a1; o.z = a2; o.w = a3;
        *(float4*)(out + qbase + lane * 4) = o;
    }
}

// ---------------- fallback (R3, f32, no workspace) ----------------
__global__ __launch_bounds__(256)
void wayfinder_attn_f32(const float* __restrict__ q,
                        const float* __restrict__ k,
                        const float* __restrict__ v,
                        const float* __restrict__ etb,
                        const int*   __restrict__ neigh_idx,
                        const int*   __restrict__ edge_type,
                        float*       __restrict__ out)
{
    __shared__ int   j_s[4][NB];
    __shared__ float w_s[4][NB];

    const int lane = threadIdx.x & 63;
    const int wave = threadIdx.x >> 6;
    const int wq   = blockIdx.x * 4 + wave;
    const int t    = wq & (T_DIM - 1);
    const long long qbase    = (long long)wq * DH;
    const long long headbase = (long long)(wq - t) * DH;

    const long long nbase = (long long)wq * NB;
    const int raw = neigh_idx[nbase + lane];
    const int et  = edge_type[nbase + lane];
    const bool valid = (raw >= 0) && (raw <= t);
    const int  sj   = min(max(raw, 0), T_DIM - 1);
    j_s[wave][lane] = sj;

    const int c = lane & 15;
    const int g = lane >> 4;
    const float4 qv = *(const float4*)(q + qbase + c * 4);

    int jarr[16];
    {
        const int4* jg = (const int4*)&j_s[wave][g * 16];
        *(int4*)&jarr[0]  = jg[0];
        *(int4*)&jarr[4]  = jg[1];
        *(int4*)&jarr[8]  = jg[2];
        *(int4*)&jarr[12] = jg[3];
    }

    const float* __restrict__ khead = k + headbase;
    float mydot = 0.f;
    #pragma unroll
    for (int i = 0; i < 16; ++i) {
        const float4 kv = *(const float4*)(khead + (long long)jarr[i] * DH + c * 4);
        float p = kv.x * qv.x + kv.y * qv.y + kv.z * qv.z + kv.w * qv.w;
        p += __shfl_xor(p, 1, 64);
        p += __shfl_xor(p, 2, 64);
        p += __shfl_xor(p, 4, 64);
        p += __shfl_xor(p, 8, 64);
        if (c == i) mydot = p;
    }

    const float bias  = (et != 0) ? etb[et - 1] : 0.f;
    const float score = valid ? (mydot * 0.125f + bias) : -INFINITY;

    float m = score;
    #pragma unroll
    for (int o = 32; o > 0; o >>= 1) m = fmaxf(m, __shfl_xor(m, o, 64));
    const float e = valid ? __expf(score - m) : 0.f;
    float s = e;
    #pragma unroll
    for (int o = 32; o > 0; o >>= 1) s += __shfl_xor(s, o, 64);
    const float w = e / fmaxf(s, 1e-20f);
    w_s[wave][lane] = w;

    const float* __restrict__ vhead = v + headbase;
    float acc = 0.f;
    #pragma unroll
    for (int d4 = 0; d4 < 16; ++d4) {
        const float4 wd = *(const float4*)&w_s[wave][d4 * 4];
        const int4   jd = *(const int4*)&j_s[wave][d4 * 4];
        acc += wd.x * vhead[(long long)jd.x * DH + lane];
        acc += wd.y * vhead[(long long)jd.y * DH + lane];
        acc += wd.z * vhead[(long long)jd.z * DH + lane];
        acc += wd.w * vhead[(long long)jd.w * DH + lane];
    }
    out[qbase + lane] = acc;
}

extern "C" void kernel_launch(void* const* d_in, const int* in_sizes, int n_in,
                              void* d_out, int out_size, void* d_ws, size_t ws_size,
                              hipStream_t stream)
{
    const float* q   = (const float*)d_in[0];
    const float* k   = (const float*)d_in[1];
    const float* v   = (const float*)d_in[2];
    const float* etb = (const float*)d_in[3];
    const int* neigh_idx = (const int*)d_in[4];
    const int* edge_type = (const int*)d_in[5];
    float* out = (float*)d_out;

    const int total_queries = 16 * T_DIM;     // 32768
    const size_t need = (size_t)KV_ELEMS * 2 * sizeof(unsigned short); // 8 MB

    if (ws_size >= need) {
        unsigned int* ws = (unsigned int*)d_ws;
        hipLaunchKernelGGL(convert_kv_kernel, dim3(KV_ELEMS / 4 / 256), dim3(256),
                           0, stream, k, v, ws);
        hipLaunchKernelGGL(wayfinder_attn_f16, dim3(total_queries / WPB),
                           dim3(WPB * 64), 0, stream,
                           q, ws, etb, neigh_idx, edge_type, out);
    } else {
        hipLaunchKernelGGL(wayfinder_attn_f32, dim3(total_queries / 4), dim3(256),
                           0, stream, q, k, v, etb, neigh_idx, edge_type, out);
    }
}